// Round 8
// baseline (276.365 us; speedup 1.0000x reference)
//
#include <hip/hip_runtime.h>
#include <hip/hip_bf16.h>

typedef __bf16 bf16x8 __attribute__((ext_vector_type(8)));
typedef float f32x4 __attribute__((ext_vector_type(4)));
typedef unsigned short ushort8 __attribute__((ext_vector_type(8)));
typedef unsigned short ushort_t;

#define AS3(p) ((__attribute__((address_space(3))) void*)(p))
#define AS1(p) ((const __attribute__((address_space(1))) void*)(p))

constexpr int L = 8192;
constexpr int C = 1024;   // = H*D
constexpr int T = 8;
constexpr int S = 1024;   // L / T
constexpr int KT_C = 32;  // C / 32

__device__ __forceinline__ float bf2f(ushort_t u) {
    return __uint_as_float(((unsigned)u) << 16);
}
__device__ __forceinline__ ushort_t f2bf(float f) {
    unsigned x = __float_as_uint(f);
    unsigned r = (x + 0x7fffu + ((x >> 16) & 1u)) >> 16;  // RNE
    return (ushort_t)r;
}

// ---------------- f32 -> bf16 convert -----------------------------------------
__global__ __launch_bounds__(256) void cvt_kernel(const float* __restrict__ in,
                                                  ushort_t* __restrict__ out, int n8) {
    int i = blockIdx.x * 256 + threadIdx.x;
    if (i >= n8) return;
    const float4* p = (const float4*)in + (long)i * 2;
    float4 a = p[0], b = p[1];
    ushort8 o;
    o[0] = f2bf(a.x); o[1] = f2bf(a.y); o[2] = f2bf(a.z); o[3] = f2bf(a.w);
    o[4] = f2bf(b.x); o[5] = f2bf(b.y); o[6] = f2bf(b.z); o[7] = f2bf(b.w);
    ((ushort8*)out)[i] = o;
}

// ---------------- W [K][N] f32 -> Wt [N][K] bf16 (4 matrices) ------------------
__global__ __launch_bounds__(256) void transpose4_kernel(
    const float* __restrict__ w0, const float* __restrict__ w1,
    const float* __restrict__ w2, const float* __restrict__ w3,
    ushort_t* __restrict__ o0, ushort_t* __restrict__ o1,
    ushort_t* __restrict__ o2, ushort_t* __restrict__ o3) {
    int z = blockIdx.z;
    const float* W = z == 0 ? w0 : z == 1 ? w1 : z == 2 ? w2 : w3;
    ushort_t* O    = z == 0 ? o0 : z == 1 ? o1 : z == 2 ? o2 : o3;
    __shared__ float tile[32][33];
    int tx = threadIdx.x & 31, ty = threadIdx.x >> 5;
    int bx = blockIdx.x * 32, by = blockIdx.y * 32;
#pragma unroll
    for (int i = 0; i < 32; i += 8)
        tile[ty + i][tx] = W[(long)(by + ty + i) * C + bx + tx];
    __syncthreads();
#pragma unroll
    for (int i = 0; i < 32; i += 8)
        O[(long)(bx + ty + i) * C + by + tx] = f2bf(tile[tx][ty + i]);
}

// ---------------- GEMM: A[M,K] bf16 x Bt[N,K] bf16, BM=BN=256, BK=32 -----------
// 512 thr, 8 waves (2M x 4N), per-wave 128x64 (acc[8][4]).  4 LDS slots x 32KB
// (A 16KB + B 16KB): 2-tile prefetch depth -> steady s_waitcnt vmcnt(8), one
// barrier per K-iter.  Bank swizzle: slot = (lane>>4) ^ ((row>>1)&3) applied as
// inverse-swizzled GLOBAL source + swizzled ds_read (linear global_load_lds
// dest) -> 2 lanes/bank-quad within each 16-lane phase group (free).
// OUT_MODE: 0 = f32 [L][C], 1 = bf16 head-major [H][L][64].
#define VMW(n) asm volatile("s_waitcnt vmcnt(" #n ")" ::: "memory")

template <int OUT_MODE>
__device__ __forceinline__ void gemm256_body(const ushort_t* __restrict__ A,
                                             const ushort_t* __restrict__ Bt,
                                             const float* __restrict__ bias,
                                             void* __restrict__ Cv,
                                             int bx, int by) {
    __shared__ char lds[4 * 32768];
    const int tid = threadIdx.x;
    const int wave = tid >> 6, lane = tid & 63;
    const int wm = wave >> 2, wn = wave & 3;
    const long bm0 = (long)bx * 256, bn0 = (long)by * 256;

    const char* Ab = (const char*)A;
    const char* Bb = (const char*)Bt;
    long aSrc[2], bSrc[2];
#pragma unroll
    for (int j = 0; j < 2; j++) {
        int c = tid + j * 512, row = c >> 2, scol = (c & 3) ^ ((row >> 1) & 3);
        aSrc[j] = (bm0 + row) * (long)(C * 2) + scol * 16;
        bSrc[j] = (bn0 + row) * (long)(C * 2) + scol * 16;
    }
    const unsigned dOff = wave * 1024u;  // + lane*16 added by HW

#define STG(slot, it)                                                            \
    do {                                                                         \
        const long kb_ = (long)(it) * 64;                                        \
        char* s_ = lds + (slot) * 32768;                                         \
        __builtin_amdgcn_global_load_lds(AS1(Ab + aSrc[0] + kb_),                \
                                         AS3(s_ + dOff), 16, 0, 0);              \
        __builtin_amdgcn_global_load_lds(AS1(Ab + aSrc[1] + kb_),                \
                                         AS3(s_ + 8192 + dOff), 16, 0, 0);       \
        __builtin_amdgcn_global_load_lds(AS1(Bb + bSrc[0] + kb_),                \
                                         AS3(s_ + 16384 + dOff), 16, 0, 0);      \
        __builtin_amdgcn_global_load_lds(AS1(Bb + bSrc[1] + kb_),                \
                                         AS3(s_ + 24576 + dOff), 16, 0, 0);      \
    } while (0)

    const unsigned sl = ((lane >> 4) ^ ((lane >> 1) & 3)) * 16u;
    const unsigned rdA = (wm * 128 + (lane & 15)) * 64u + sl;
    const unsigned rdB = 16384u + (wn * 64 + (lane & 15)) * 64u + sl;

    f32x4 acc[8][4] = {};

    STG(0, 0); STG(1, 1); STG(2, 2);
    VMW(8);
    __builtin_amdgcn_s_barrier();

    for (int it = 0; it < KT_C; ++it) {
        if (it + 3 < KT_C) STG((it + 3) & 3, it + 3);
        const char* bs = lds + (it & 3) * 32768;
        bf16x8 af[8], bfr[4];
#pragma unroll
        for (int q = 0; q < 8; q++) af[q] = *(const bf16x8*)(bs + rdA + q * 1024);
#pragma unroll
        for (int j = 0; j < 4; j++) bfr[j] = *(const bf16x8*)(bs + rdB + j * 1024);

        __builtin_amdgcn_s_setprio(1);
#pragma unroll
        for (int q = 0; q < 8; q++)
#pragma unroll
            for (int j = 0; j < 4; j++)
                acc[q][j] = __builtin_amdgcn_mfma_f32_16x16x32_bf16(af[q], bfr[j],
                                                                    acc[q][j], 0, 0, 0);
        __builtin_amdgcn_s_setprio(0);

        if (it + 3 < KT_C)      { VMW(8); }   // tile it+1 retired, it+2/it+3 in flight
        else if (it + 2 < KT_C) { VMW(4); }
        else if (it + 1 < KT_C) { VMW(0); }
        if (it + 1 < KT_C) __builtin_amdgcn_s_barrier();
    }

    // epilogue: C/D layout col=lane&15, row=(lane>>4)*4+r
    const int r0 = (int)bm0 + wm * 128 + (lane >> 4) * 4;
    const int c0 = (int)bn0 + wn * 64 + (lane & 15);
#pragma unroll
    for (int j = 0; j < 4; j++) {
        const int col = c0 + j * 16;
        const float bia = bias[col];
#pragma unroll
        for (int q = 0; q < 8; q++) {
            const int row = r0 + q * 16;
#pragma unroll
            for (int r = 0; r < 4; r++) {
                float val = acc[q][j][r] + bia;
                if (OUT_MODE == 1)  // bf16 head-major [H][L][64]
                    ((ushort_t*)Cv)[(size_t)(col >> 6) * (L * 64) +
                                    (long)(row + r) * 64 + (col & 63)] = f2bf(val);
                else
                    ((float*)Cv)[(long)(row + r) * C + col] = val;
            }
        }
    }
#undef STG
}

__global__ __launch_bounds__(512, 2) void gemm_qkv_kernel(
    const ushort_t* __restrict__ xbf,
    const ushort_t* __restrict__ WqT, const ushort_t* __restrict__ WkT,
    const ushort_t* __restrict__ WvT,
    const float* __restrict__ bq, const float* __restrict__ bk,
    const float* __restrict__ bv,
    ushort_t* __restrict__ q, ushort_t* __restrict__ k, ushort_t* __restrict__ v) {
    const int z = blockIdx.z;
    const ushort_t* Bt = z == 0 ? WqT : z == 1 ? WkT : WvT;
    const float* bias  = z == 0 ? bq : z == 1 ? bk : bv;
    ushort_t* out      = z == 0 ? q : z == 1 ? k : v;
    gemm256_body<1>(xbf, Bt, bias, out, blockIdx.x, blockIdx.y);
}

__global__ __launch_bounds__(512, 2) void gemm_o_kernel(
    const ushort_t* __restrict__ a, const ushort_t* __restrict__ WoT,
    const float* __restrict__ bo, float* __restrict__ outp) {
    gemm256_body<0>(a, WoT, bo, outp, blockIdx.x, blockIdx.y);
}

// ---------------- per-row rsqrt precompute (q and k, head-major inputs) --------
__global__ __launch_bounds__(256) void rownorm_kernel(
    const ushort_t* __restrict__ q, const ushort_t* __restrict__ k,
    float* __restrict__ rq, float* __restrict__ rk) {
    const int wave = threadIdx.x >> 6, lane = threadIdx.x & 63;
    const int p = blockIdx.x * 4 + wave;
    const int h = lane >> 2, qt = lane & 3;
    const size_t base = (size_t)h * (L * 64) + (long)p * 64 + qt * 16;
    const ushort8* qp = (const ushort8*)(q + base);
    const ushort8* kp = (const ushort8*)(k + base);
    ushort8 qa = qp[0], qb = qp[1], ka = kp[0], kb = kp[1];
    float sq = 0.f, sk = 0.f;
#pragma unroll
    for (int j = 0; j < 8; j++) {
        float a = bf2f(qa[j]), b = bf2f(qb[j]);
        sq += a * a + b * b;
        float c2 = bf2f(ka[j]), d = bf2f(kb[j]);
        sk += c2 * c2 + d * d;
    }
#pragma unroll
    for (int m = 1; m < 64; m <<= 1) { sq += __shfl_xor(sq, m); sk += __shfl_xor(sk, m); }
    if (lane == 0) {
        rq[p] = rsqrtf(sq * (1.0f / C) + 1e-6f);
        rk[p] = rsqrtf(sk * (1.0f / C) + 1e-6f);
    }
}

// ---------------- fused small-world attention (head-major q/k/v) ---------------
// block = (frame t = bid&7 -> XCD-affine, chunk of 32 positions, head h slow):
// per-XCD hot set = one (t,h) k+v slice = 512KB (L2-resident); in-block row
// reuse hits L1.  8 lanes per position x 8 ch each; 128B coalesced row reads.
__global__ __launch_bounds__(256) void attn_kernel(
    const ushort_t* __restrict__ qraw, const ushort_t* __restrict__ kraw,
    const ushort_t* __restrict__ vraw,
    const float* __restrict__ qn_w, const float* __restrict__ kn_w,
    const float* __restrict__ eb, const float* __restrict__ rqA,
    const float* __restrict__ rkA, ushort_t* __restrict__ outp) {
    const int bid = blockIdx.x;
    const int t = bid & 7, chunk = (bid >> 3) & 31, h = bid >> 8;
    const int wave = threadIdx.x >> 6, lane = threadIdx.x & 63;
    const int pos = lane >> 3, cg = lane & 7;
    const int s = chunk * 32 + wave * 8 + pos;
    const int p = (t << 10) | s;

    const ushort_t* qb = qraw + (size_t)h * (L * 64);
    const ushort_t* kb = kraw + (size_t)h * (L * 64);
    const ushort_t* vb = vraw + (size_t)h * (L * 64);

    // q fragment (8 ch), scaled by rq * qn_w * kn_w
    float qf[8];
    {
        ushort8 qv = *(const ushort8*)(qb + (long)p * 64 + cg * 8);
        const float rqv = rqA[p];
#pragma unroll
        for (int j = 0; j < 8; j++)
            qf[j] = bf2f(qv[j]) * rqv * qn_w[h * 64 + cg * 8 + j] * kn_w[h * 64 + cg * 8 + j];
    }

    // neighbor positions: 12 spatial + 4 temporal
    const int SHF[16] = {1, -1, 2, -2, 4, -4, 8, -8, 16, -16, 32, -32, 1, -1, 2, -2};
    int pp[16];
#pragma unroll
    for (int n = 0; n < 16; n++) {
        if (n < 12) pp[n] = (t << 10) | ((s + SHF[n]) & (S - 1));
        else        pp[n] = (((t + SHF[n]) & (T - 1)) << 10) | s;
    }

    // scores: 8-ch partial dot, reduce over the 8 lanes of this position
    float sc[16];
#pragma unroll
    for (int n = 0; n < 16; n++) {
        ushort8 kv = *(const ushort8*)(kb + (long)pp[n] * 64 + cg * 8);
        float dot = 0.f;
#pragma unroll
        for (int j = 0; j < 8; j++) dot += qf[j] * bf2f(kv[j]);
        dot += __shfl_xor(dot, 1);
        dot += __shfl_xor(dot, 2);
        dot += __shfl_xor(dot, 4);
        sc[n] = dot * (rkA[pp[n]] * 0.125f) + eb[h * 16 + n];
    }

    // softmax over 16 shifts (8 lanes/position redundant but uniform)
    float mx = sc[0];
#pragma unroll
    for (int n = 1; n < 16; n++) mx = fmaxf(mx, sc[n]);
    float wts[16], den = 0.f;
#pragma unroll
    for (int n = 0; n < 16; n++) { wts[n] = __expf(sc[n] - mx); den += wts[n]; }
    const float inv = 1.0f / den;

    // weighted V
    float o[8] = {};
#pragma unroll
    for (int n = 0; n < 16; n++) {
        ushort8 vv = *(const ushort8*)(vb + (long)pp[n] * 64 + cg * 8);
#pragma unroll
        for (int j = 0; j < 8; j++) o[j] += wts[n] * bf2f(vv[j]);
    }

    ushort8 ov;
#pragma unroll
    for (int j = 0; j < 8; j++) ov[j] = f2bf(o[j] * inv);
    *(ushort8*)(outp + (long)p * C + h * 64 + cg * 8) = ov;  // aout is [L][C]
}

// ---------------- launch --------------------------------------------------------
extern "C" void kernel_launch(void* const* d_in, const int* in_sizes, int n_in,
                              void* d_out, int out_size, void* d_ws, size_t ws_size,
                              hipStream_t stream) {
    const float* x    = (const float*)d_in[0];
    const float* Wq   = (const float*)d_in[1];
    const float* bq   = (const float*)d_in[2];
    const float* Wk   = (const float*)d_in[3];
    const float* bk   = (const float*)d_in[4];
    const float* Wv   = (const float*)d_in[5];
    const float* bv   = (const float*)d_in[6];
    const float* qn_w = (const float*)d_in[7];
    const float* kn_w = (const float*)d_in[8];
    const float* eb   = (const float*)d_in[9];
    const float* Wo   = (const float*)d_in[10];
    const float* bo   = (const float*)d_in[11];

    char* ws = (char*)d_ws;
    ushort_t* xbf  = (ushort_t*)ws;                               // 16 MB
    ushort_t* WqT  = (ushort_t*)(ws + (size_t)L * C * 2);         // 4 x 2 MB
    ushort_t* WkT  = WqT + (size_t)C * C;
    ushort_t* WvT  = WkT + (size_t)C * C;
    ushort_t* WoT  = WvT + (size_t)C * C;
    ushort_t* qraw = WoT + (size_t)C * C;                         // 3 x 16 MB ([H][L][64])
    ushort_t* kraw = qraw + (size_t)L * C;
    ushort_t* vraw = kraw + (size_t)L * C;
    ushort_t* aout = vraw + (size_t)L * C;                        // 16 MB ([L][C])
    float* rqArr   = (float*)(aout + (size_t)L * C);              // 32 KB
    float* rkArr   = rqArr + L;                                   // 32 KB
    float* outp = (float*)d_out;

    cvt_kernel<<<(L * C / 8 + 255) / 256, 256, 0, stream>>>(x, xbf, L * C / 8);
    transpose4_kernel<<<dim3(32, 32, 4), 256, 0, stream>>>(Wq, Wk, Wv, Wo,
                                                           WqT, WkT, WvT, WoT);
    gemm_qkv_kernel<<<dim3(L / 256, C / 256, 3), 512, 0, stream>>>(
        xbf, WqT, WkT, WvT, bq, bk, bv, qraw, kraw, vraw);
    rownorm_kernel<<<L / 4, 256, 0, stream>>>(qraw, kraw, rqArr, rkArr);
    attn_kernel<<<T * 32 * 16, 256, 0, stream>>>(qraw, kraw, vraw, qn_w, kn_w, eb,
                                                 rqArr, rkArr, aout);
    gemm_o_kernel<<<dim3(L / 256, C / 256), 512, 0, stream>>>(aout, WoT, bo, outp);
}

// Round 10
// 253.238 us; speedup vs baseline: 1.0913x; 1.0913x over previous
//
#include <hip/hip_runtime.h>
#include <hip/hip_bf16.h>

typedef __bf16 bf16x8 __attribute__((ext_vector_type(8)));
typedef float f32x4 __attribute__((ext_vector_type(4)));
typedef unsigned short ushort8 __attribute__((ext_vector_type(8)));
typedef unsigned short ushort_t;

#define AS3(p) ((__attribute__((address_space(3))) void*)(p))
#define AS1(p) ((const __attribute__((address_space(1))) void*)(p))

constexpr int L = 8192;
constexpr int C = 1024;   // = H*D
constexpr int T = 8;
constexpr int S = 1024;   // L / T
constexpr int KT_C = 32;  // C / 32

__device__ __forceinline__ float bf2f(ushort_t u) {
    return __uint_as_float(((unsigned)u) << 16);
}
__device__ __forceinline__ ushort_t f2bf(float f) {
    unsigned x = __float_as_uint(f);
    unsigned r = (x + 0x7fffu + ((x >> 16) & 1u)) >> 16;  // RNE
    return (ushort_t)r;
}

// ---------------- f32 -> bf16 convert -----------------------------------------
__global__ __launch_bounds__(256) void cvt_kernel(const float* __restrict__ in,
                                                  ushort_t* __restrict__ out, int n8) {
    int i = blockIdx.x * 256 + threadIdx.x;
    if (i >= n8) return;
    const float4* p = (const float4*)in + (long)i * 2;
    float4 a = p[0], b = p[1];
    ushort8 o;
    o[0] = f2bf(a.x); o[1] = f2bf(a.y); o[2] = f2bf(a.z); o[3] = f2bf(a.w);
    o[4] = f2bf(b.x); o[5] = f2bf(b.y); o[6] = f2bf(b.z); o[7] = f2bf(b.w);
    ((ushort8*)out)[i] = o;
}

// ---------------- W [K][N] f32 -> Wt [N][K] bf16 (4 matrices) ------------------
__global__ __launch_bounds__(256) void transpose4_kernel(
    const float* __restrict__ w0, const float* __restrict__ w1,
    const float* __restrict__ w2, const float* __restrict__ w3,
    ushort_t* __restrict__ o0, ushort_t* __restrict__ o1,
    ushort_t* __restrict__ o2, ushort_t* __restrict__ o3) {
    int z = blockIdx.z;
    const float* W = z == 0 ? w0 : z == 1 ? w1 : z == 2 ? w2 : w3;
    ushort_t* O    = z == 0 ? o0 : z == 1 ? o1 : z == 2 ? o2 : o3;
    __shared__ float tile[32][33];
    int tx = threadIdx.x & 31, ty = threadIdx.x >> 5;
    int bx = blockIdx.x * 32, by = blockIdx.y * 32;
#pragma unroll
    for (int i = 0; i < 32; i += 8)
        tile[ty + i][tx] = W[(long)(by + ty + i) * C + bx + tx];
    __syncthreads();
#pragma unroll
    for (int i = 0; i < 32; i += 8)
        O[(long)(bx + ty + i) * C + by + tx] = f2bf(tile[tx][ty + i]);
}

// ---------------- GEMM: A[M,K] bf16 x Bt[N,K] bf16, BM=128, BN=256, BK=32 ------
// 256 thr / 4 waves (1M x 4N), per-wave 128x64 = acc[8][4].  3 slots x 24KB
// (A 8KB + B 16KB) = 72KB -> 2 blocks/CU.  2-deep prefetch: stage tile it+2
// during iter it; steady end-iter s_waitcnt vmcnt(6) (6 loads/thread/tile).
// 2 phases x 16 MFMA per iter, each {ds_read || stage || barrier || lgkmcnt(0)
// || setprio MFMA}.  Bank swizzle: physcol = kslot ^ ((row>>1)&3), applied as
// inverse-swizzled GLOBAL source + swizzled ds_read (linear gload_lds dest)
// -> 2 lanes/bank-granule per 16-lane phase group (free; R8 measured 0).
// OUT_MODE: 0 = f32 [L][C], 1 = bf16 head-major [H][L][64].
#define VMW(n) asm volatile("s_waitcnt vmcnt(" #n ")" ::: "memory")
#define GBAR() __builtin_amdgcn_s_barrier()
#define LGKM0() asm volatile("s_waitcnt lgkmcnt(0)" ::: "memory")

template <int OUT_MODE>
__device__ __forceinline__ void gemm_body(const ushort_t* __restrict__ A,
                                          const ushort_t* __restrict__ Bt,
                                          const float* __restrict__ bias,
                                          void* __restrict__ Cv,
                                          int bx, int by) {
    __shared__ char lds[3 * 24576];
    const int tid = threadIdx.x;
    const int wave = tid >> 6, lane = tid & 63;
    const long bm0 = (long)bx * 128, bn0 = (long)by * 256;

    const char* Ab = (const char*)A;
    const char* Bb = (const char*)Bt;
    long aSrc[2], bSrc[4];
#pragma unroll
    for (int j = 0; j < 2; j++) {
        int c = tid + j * 256, row = c >> 2, scol = (c & 3) ^ ((row >> 1) & 3);
        aSrc[j] = (bm0 + row) * (long)(C * 2) + scol * 16;
    }
#pragma unroll
    for (int j = 0; j < 4; j++) {
        int c = tid + j * 256, row = c >> 2, scol = (c & 3) ^ ((row >> 1) & 3);
        bSrc[j] = (bn0 + row) * (long)(C * 2) + scol * 16;
    }
    const unsigned wOff = wave * 1024u;  // + lane*16 added by HW

#define STG_A(slot, itx)                                                         \
    do {                                                                         \
        const long kb_ = (long)(itx) * 64;                                       \
        char* s_ = lds + (slot) * 24576;                                         \
        __builtin_amdgcn_global_load_lds(AS1(Ab + aSrc[0] + kb_),                \
                                         AS3(s_ + wOff), 16, 0, 0);              \
        __builtin_amdgcn_global_load_lds(AS1(Ab + aSrc[1] + kb_),                \
                                         AS3(s_ + 4096 + wOff), 16, 0, 0);       \
    } while (0)
#define STG_B1(slot, itx)                                                        \
    do {                                                                         \
        const long kb_ = (long)(itx) * 64;                                       \
        char* s_ = lds + (slot) * 24576;                                         \
        __builtin_amdgcn_global_load_lds(AS1(Bb + bSrc[0] + kb_),                \
                                         AS3(s_ + 8192 + wOff), 16, 0, 0);       \
    } while (0)
#define STG_B3(slot, itx)                                                        \
    do {                                                                         \
        const long kb_ = (long)(itx) * 64;                                       \
        char* s_ = lds + (slot) * 24576;                                         \
        __builtin_amdgcn_global_load_lds(AS1(Bb + bSrc[1] + kb_),                \
                                         AS3(s_ + 12288 + wOff), 16, 0, 0);      \
        __builtin_amdgcn_global_load_lds(AS1(Bb + bSrc[2] + kb_),                \
                                         AS3(s_ + 16384 + wOff), 16, 0, 0);      \
        __builtin_amdgcn_global_load_lds(AS1(Bb + bSrc[3] + kb_),                \
                                         AS3(s_ + 20480 + wOff), 16, 0, 0);      \
    } while (0)

    const unsigned sl = ((lane >> 4) ^ ((lane >> 1) & 3)) * 16u;
    const unsigned rdA = (lane & 15) * 64u + sl;
    const unsigned rdB = 8192u + (wave * 64 + (lane & 15)) * 64u + sl;

    f32x4 acc[8][4] = {};
    bf16x8 af0[4], af1[4], bfr[4];

    // prologue: stage tiles 0 (slot0) and 1 (slot1)
    STG_A(0, 0); STG_B1(0, 0); STG_B3(0, 0);
    STG_A(1, 1); STG_B1(1, 1); STG_B3(1, 1);
    VMW(6);   // tile 0 complete (tile 1's 6 in flight)
    GBAR();

    int cs = 0;
    for (int it = 0; it < KT_C; ++it) {
        const int s2 = (cs >= 1) ? cs - 1 : 2;  // (it+2)%3
        const char* bs = lds + cs * 24576;
        const bool stg = (it + 2 < KT_C);

        // ---- phase 0: A rows 0..63 frags + all B frags; stage A + B0
#pragma unroll
        for (int q = 0; q < 4; q++) af0[q] = *(const bf16x8*)(bs + rdA + q * 1024);
#pragma unroll
        for (int j = 0; j < 4; j++) bfr[j] = *(const bf16x8*)(bs + rdB + j * 1024);
        if (stg) { STG_A(s2, it + 2); STG_B1(s2, it + 2); }
        GBAR();
        LGKM0();
        __builtin_amdgcn_s_setprio(1);
#pragma unroll
        for (int q = 0; q < 4; q++)
#pragma unroll
            for (int j = 0; j < 4; j++)
                acc[q][j] = __builtin_amdgcn_mfma_f32_16x16x32_bf16(af0[q], bfr[j],
                                                                    acc[q][j], 0, 0, 0);
        __builtin_amdgcn_s_setprio(0);
        GBAR();

        // ---- phase 1: A rows 64..127 frags; stage B1..3
#pragma unroll
        for (int q = 0; q < 4; q++) af1[q] = *(const bf16x8*)(bs + rdA + (4 + q) * 1024);
        if (stg) STG_B3(s2, it + 2);
        GBAR();
        LGKM0();
        __builtin_amdgcn_s_setprio(1);
#pragma unroll
        for (int q = 0; q < 4; q++)
#pragma unroll
            for (int j = 0; j < 4; j++)
                acc[4 + q][j] = __builtin_amdgcn_mfma_f32_16x16x32_bf16(af1[q], bfr[j],
                                                                        acc[4 + q][j], 0, 0, 0);
        __builtin_amdgcn_s_setprio(0);

        // ---- iter end: counted wait for tile it+1; barrier protects slot reuse
        if (stg)                 { VMW(6); }
        else if (it + 1 < KT_C)  { VMW(0); }
        if (it + 1 < KT_C) GBAR();
        cs = (cs >= 2) ? 0 : cs + 1;
    }

    // epilogue: C/D layout col=lane&15, row=(lane>>4)*4+r
    const int r0 = (int)bm0 + (lane >> 4) * 4;
    const int c0 = (int)bn0 + wave * 64 + (lane & 15);
#pragma unroll
    for (int j = 0; j < 4; j++) {
        const int col = c0 + j * 16;
        const float bia = bias[col];
#pragma unroll
        for (int q = 0; q < 8; q++) {
            const int row = r0 + q * 16;
#pragma unroll
            for (int r = 0; r < 4; r++) {
                float val = acc[q][j][r] + bia;
                if (OUT_MODE == 1)  // bf16 head-major [H][L][64]
                    ((ushort_t*)Cv)[(size_t)(col >> 6) * (L * 64) +
                                    (long)(row + r) * 64 + (col & 63)] = f2bf(val);
                else
                    ((float*)Cv)[(long)(row + r) * C + col] = val;
            }
        }
    }
#undef STG_A
#undef STG_B1
#undef STG_B3
}

__global__ __launch_bounds__(256, 2) void gemm_qkv_kernel(
    const ushort_t* __restrict__ xbf,
    const ushort_t* __restrict__ WqT, const ushort_t* __restrict__ WkT,
    const ushort_t* __restrict__ WvT,
    const float* __restrict__ bq, const float* __restrict__ bk,
    const float* __restrict__ bv,
    ushort_t* __restrict__ q, ushort_t* __restrict__ k, ushort_t* __restrict__ v) {
    const int z = blockIdx.z;
    const ushort_t* Bt = z == 0 ? WqT : z == 1 ? WkT : WvT;
    const float* bias  = z == 0 ? bq : z == 1 ? bk : bv;
    ushort_t* out      = z == 0 ? q : z == 1 ? k : v;
    gemm_body<1>(xbf, Bt, bias, out, blockIdx.x, blockIdx.y);
}

__global__ __launch_bounds__(256, 2) void gemm_o_kernel(
    const ushort_t* __restrict__ a, const ushort_t* __restrict__ WoT,
    const float* __restrict__ bo, float* __restrict__ outp) {
    gemm_body<0>(a, WoT, bo, outp, blockIdx.x, blockIdx.y);
}

// ---------------- per-row rsqrt precompute (q and k, head-major inputs) --------
__global__ __launch_bounds__(256) void rownorm_kernel(
    const ushort_t* __restrict__ q, const ushort_t* __restrict__ k,
    float* __restrict__ rq, float* __restrict__ rk) {
    const int wave = threadIdx.x >> 6, lane = threadIdx.x & 63;
    const int p = blockIdx.x * 4 + wave;
    const int h = lane >> 2, qt = lane & 3;
    const size_t base = (size_t)h * (L * 64) + (long)p * 64 + qt * 16;
    const ushort8* qp = (const ushort8*)(q + base);
    const ushort8* kp = (const ushort8*)(k + base);
    ushort8 qa = qp[0], qb = qp[1], ka = kp[0], kb = kp[1];
    float sq = 0.f, sk = 0.f;
#pragma unroll
    for (int j = 0; j < 8; j++) {
        float a = bf2f(qa[j]), b = bf2f(qb[j]);
        sq += a * a + b * b;
        float c2 = bf2f(ka[j]), d = bf2f(kb[j]);
        sk += c2 * c2 + d * d;
    }
#pragma unroll
    for (int m = 1; m < 64; m <<= 1) { sq += __shfl_xor(sq, m); sk += __shfl_xor(sk, m); }
    if (lane == 0) {
        rq[p] = rsqrtf(sq * (1.0f / C) + 1e-6f);
        rk[p] = rsqrtf(sk * (1.0f / C) + 1e-6f);
    }
}

// ---------------- fused small-world attention (head-major q/k/v) ---------------
// block = (frame t = bid&7 -> XCD-affine, chunk of 32 positions, head h slow):
// per-XCD hot set = one (t,h) k+v slice = 512KB (L2-resident); in-block row
// reuse hits L1.  8 lanes per position x 8 ch each; coalesced row reads.
__global__ __launch_bounds__(256) void attn_kernel(
    const ushort_t* __restrict__ qraw, const ushort_t* __restrict__ kraw,
    const ushort_t* __restrict__ vraw,
    const float* __restrict__ qn_w, const float* __restrict__ kn_w,
    const float* __restrict__ eb, const float* __restrict__ rqA,
    const float* __restrict__ rkA, ushort_t* __restrict__ outp) {
    const int bid = blockIdx.x;
    const int t = bid & 7, chunk = (bid >> 3) & 31, h = bid >> 8;
    const int wave = threadIdx.x >> 6, lane = threadIdx.x & 63;
    const int pos = lane >> 3, cg = lane & 7;
    const int s = chunk * 32 + wave * 8 + pos;
    const int p = (t << 10) | s;

    const ushort_t* qb = qraw + (size_t)h * (L * 64);
    const ushort_t* kb = kraw + (size_t)h * (L * 64);
    const ushort_t* vb = vraw + (size_t)h * (L * 64);

    // q fragment (8 ch), scaled by rq * qn_w * kn_w
    float qf[8];
    {
        ushort8 qv = *(const ushort8*)(qb + (long)p * 64 + cg * 8);
        const float rqv = rqA[p];
#pragma unroll
        for (int j = 0; j < 8; j++)
            qf[j] = bf2f(qv[j]) * rqv * qn_w[h * 64 + cg * 8 + j] * kn_w[h * 64 + cg * 8 + j];
    }

    // neighbor positions: 12 spatial + 4 temporal
    const int SHF[16] = {1, -1, 2, -2, 4, -4, 8, -8, 16, -16, 32, -32, 1, -1, 2, -2};
    int pp[16];
#pragma unroll
    for (int n = 0; n < 16; n++) {
        if (n < 12) pp[n] = (t << 10) | ((s + SHF[n]) & (S - 1));
        else        pp[n] = (((t + SHF[n]) & (T - 1)) << 10) | s;
    }

    // scores: 8-ch partial dot, reduce over the 8 lanes of this position
    float sc[16];
#pragma unroll
    for (int n = 0; n < 16; n++) {
        ushort8 kv = *(const ushort8*)(kb + (long)pp[n] * 64 + cg * 8);
        float dot = 0.f;
#pragma unroll
        for (int j = 0; j < 8; j++) dot += qf[j] * bf2f(kv[j]);
        dot += __shfl_xor(dot, 1);
        dot += __shfl_xor(dot, 2);
        dot += __shfl_xor(dot, 4);
        sc[n] = dot * (rkA[pp[n]] * 0.125f) + eb[h * 16 + n];
    }

    // softmax over 16 shifts (8 lanes/position redundant but uniform)
    float mx = sc[0];
#pragma unroll
    for (int n = 1; n < 16; n++) mx = fmaxf(mx, sc[n]);
    float wts[16], den = 0.f;
#pragma unroll
    for (int n = 0; n < 16; n++) { wts[n] = __expf(sc[n] - mx); den += wts[n]; }
    const float inv = 1.0f / den;

    // weighted V
    float o[8] = {};
#pragma unroll
    for (int n = 0; n < 16; n++) {
        ushort8 vv = *(const ushort8*)(vb + (long)pp[n] * 64 + cg * 8);
#pragma unroll
        for (int j = 0; j < 8; j++) o[j] += wts[n] * bf2f(vv[j]);
    }

    ushort8 ov;
#pragma unroll
    for (int j = 0; j < 8; j++) ov[j] = f2bf(o[j] * inv);
    *(ushort8*)(outp + (long)p * C + h * 64 + cg * 8) = ov;  // aout is [L][C]
}

// ---------------- launch --------------------------------------------------------
extern "C" void kernel_launch(void* const* d_in, const int* in_sizes, int n_in,
                              void* d_out, int out_size, void* d_ws, size_t ws_size,
                              hipStream_t stream) {
    const float* x    = (const float*)d_in[0];
    const float* Wq   = (const float*)d_in[1];
    const float* bq   = (const float*)d_in[2];
    const float* Wk   = (const float*)d_in[3];
    const float* bk   = (const float*)d_in[4];
    const float* Wv   = (const float*)d_in[5];
    const float* bv   = (const float*)d_in[6];
    const float* qn_w = (const float*)d_in[7];
    const float* kn_w = (const float*)d_in[8];
    const float* eb   = (const float*)d_in[9];
    const float* Wo   = (const float*)d_in[10];
    const float* bo   = (const float*)d_in[11];

    char* ws = (char*)d_ws;
    ushort_t* xbf  = (ushort_t*)ws;                               // 16 MB
    ushort_t* WqT  = (ushort_t*)(ws + (size_t)L * C * 2);         // 4 x 2 MB
    ushort_t* WkT  = WqT + (size_t)C * C;
    ushort_t* WvT  = WkT + (size_t)C * C;
    ushort_t* WoT  = WvT + (size_t)C * C;
    ushort_t* qraw = WoT + (size_t)C * C;                         // 3 x 16 MB ([H][L][64])
    ushort_t* kraw = qraw + (size_t)L * C;
    ushort_t* vraw = kraw + (size_t)L * C;
    ushort_t* aout = vraw + (size_t)L * C;                        // 16 MB ([L][C])
    float* rqArr   = (float*)(aout + (size_t)L * C);              // 32 KB
    float* rkArr   = rqArr + L;                                   // 32 KB
    float* outp = (float*)d_out;

    cvt_kernel<<<(L * C / 8 + 255) / 256, 256, 0, stream>>>(x, xbf, L * C / 8);
    transpose4_kernel<<<dim3(32, 32, 4), 256, 0, stream>>>(Wq, Wk, Wv, Wo,
                                                           WqT, WkT, WvT, WoT);
    gemm_qkv_kernel<<<dim3(L / 128, C / 256, 3), 256, 0, stream>>>(
        xbf, WqT, WkT, WvT, bq, bk, bv, qraw, kraw, vraw);
    rownorm_kernel<<<L / 4, 256, 0, stream>>>(qraw, kraw, rqArr, rkArr);
    attn_kernel<<<T * 32 * 16, 256, 0, stream>>>(qraw, kraw, vraw, qn_w, kn_w, eb,
                                                 rqArr, rkArr, aout);
    gemm_o_kernel<<<dim3(L / 128, C / 256), 256, 0, stream>>>(aout, WoT, bo, outp);
}